// Round 3
// baseline (131.520 us; speedup 1.0000x reference)
//
#include <hip/hip_runtime.h>
#include <hip/hip_bf16.h>

#define MDIM 8192
#define KDIM 512
#define BM 128
#define BN 128
#define BK 64
#define NKT 8   // K-tiles of 64

typedef __attribute__((ext_vector_type(8))) short short8;
typedef __attribute__((ext_vector_type(4))) float f32x4;
typedef __attribute__((ext_vector_type(8))) unsigned short ushort8;

__device__ __forceinline__ unsigned short f32_to_bf16_rne(float f) {
    unsigned int u = __float_as_uint(f);
    u += 0x7FFFu + ((u >> 16) & 1u);
    return (unsigned short)(u >> 16);
}
__device__ __forceinline__ float bf16_to_f32(unsigned short s) {
    return __uint_as_float(((unsigned int)s) << 16);
}

__device__ __forceinline__ void gload16(const void* g, void* l) {
    __builtin_amdgcn_global_load_lds(
        (const __attribute__((address_space(1))) void*)g,
        (__attribute__((address_space(3))) void*)l,
        16, 0, 0);
}

// Kernel 1: fp32 -> bf16 into ws + sq[row] = sum(bf16(x)^2) (fp32).
__global__ __launch_bounds__(256) void rbf_convert(const float* __restrict__ x,
                                                   unsigned short* __restrict__ xb,
                                                   float* __restrict__ sq) {
    const int lane = threadIdx.x & 63;
    const int wave = threadIdx.x >> 6;
    const int row  = blockIdx.x * 4 + wave;

    const float* xr = x + (size_t)row * KDIM + lane * 8;
    float4 v0 = *(const float4*)(xr);
    float4 v1 = *(const float4*)(xr + 4);
    float vals[8] = {v0.x, v0.y, v0.z, v0.w, v1.x, v1.y, v1.z, v1.w};

    ushort8 packed;
    float s = 0.f;
#pragma unroll
    for (int j = 0; j < 8; ++j) {
        unsigned short b = f32_to_bf16_rne(vals[j]);
        packed[j] = b;
        float f = bf16_to_f32(b);
        s += f * f;
    }
    *(ushort8*)(xb + (size_t)row * KDIM + lane * 8) = packed;

#pragma unroll
    for (int off = 32; off > 0; off >>= 1) s += __shfl_xor(s, off, 64);
    if (lane == 0) sq[row] = s;
}

// Kernel 2: 128x128 NT-GEMM tile + LDS-transposed vectorized RBF epilogue.
// 4 waves (2x2), per-wave 64x64 = 4x4 frags. 64 KiB LDS -> 2 blocks/CU so
// one block's store drain overlaps the sibling block's K-loop.
__global__ __launch_bounds__(256, 2) void rbf_gemm(const unsigned short* __restrict__ xb,
                                                   const float* __restrict__ sq,
                                                   float* __restrict__ out) {
    __shared__ char lds[65536];   // dbuf: [buf][A 16K | B 16K]; reused by epilogue

    const int t    = threadIdx.x;
    const int lane = t & 63;
    const int wave = t >> 6;
    const int wr   = wave >> 1;   // 0..1
    const int wc   = wave & 1;    // 0..1

    // XCD-clustered tile mapping: 64x64 tiles; XCD x owns 8 tile-rows.
    const int bid  = blockIdx.x;
    const int xcd  = bid & 7;
    const int idx  = bid >> 3;
    const int brow = (xcd * 8 + (idx >> 6)) * BM;
    const int bcol = (idx & 63) * BN;

    // staging: thread t -> LDS row t>>3 (+32 per issue), physical slot t&7 (linear),
    // global source slot XOR-swizzled (T2 both-sides, involution verified in R1).
    const int trow = t >> 3;                          // 0..31
    const int sx   = ((t & 7) ^ (trow & 7)) * 16;     // swizzled source byte slot

    // fragment coords
    const int fr = lane & 15;
    const int fo = lane >> 4;
    const int k7 = fr & 7;

    f32x4 acc[4][4] = {};

    const char* gA = (const char*)xb + (size_t)(brow + trow) * 1024 + sx;
    const char* gB = (const char*)xb + (size_t)(bcol + trow) * 1024 + sx;
    char* ldsw = lds + wave * 1024;   // wave-uniform base; +buf*32768 +op*16384 +u*4096

    // prologue: stage tile 0 into buf 0
#pragma unroll
    for (int u = 0; u < 4; ++u) {
        gload16(gA + (size_t)u * 32768, ldsw + u * 4096);
        gload16(gB + (size_t)u * 32768, ldsw + 16384 + u * 4096);
    }
    __syncthreads();

#pragma unroll
    for (int i = 0; i < NKT; ++i) {
        const int cb = i & 1;
        if (i < NKT - 1) {
            const size_t koff = (size_t)(i + 1) * 128;
            char* dst = ldsw + (cb ^ 1) * 32768;
#pragma unroll
            for (int u = 0; u < 4; ++u) {
                gload16(gA + (size_t)u * 32768 + koff, dst + u * 4096);
                gload16(gB + (size_t)u * 32768 + koff, dst + 16384 + u * 4096);
            }
        }
        const char* Ab = lds + cb * 32768;
        const char* Bb = lds + cb * 32768 + 16384;
#pragma unroll
        for (int ks = 0; ks < 2; ++ks) {
            const int cxa = ((ks * 4 + fo) ^ k7) * 16;
            short8 a[4];
#pragma unroll
            for (int m = 0; m < 4; ++m)
                a[m] = *(const short8*)(Ab + (wr * 64 + m * 16 + fr) * 128 + cxa);
#pragma unroll
            for (int n = 0; n < 4; ++n) {
                short8 b = *(const short8*)(Bb + (wc * 64 + n * 16 + fr) * 128 + cxa);
#pragma unroll
                for (int m = 0; m < 4; ++m)
                    acc[m][n] = __builtin_amdgcn_mfma_f32_16x16x32_bf16(a[m], b, acc[m][n], 0, 0, 0);
            }
        }
        __syncthreads();   // reads drained + next tile landed (vmcnt0+lgkm0+barrier)
    }

    // ---- epilogue: per-wave 16 KiB LDS transpose, float4 stores (256B segments) ----
    float* ldsf = (float*)lds + wave * 4096;   // 64 rows x 64 f32, 16B-group XOR swizzle
    const int cg = lane >> 4;
    const int cl = lane & 15;

    asm volatile("" ::: "memory");
#pragma unroll
    for (int m = 0; m < 4; ++m) {
#pragma unroll
        for (int j = 0; j < 4; ++j) {
            const int r = m * 16 + cg * 4 + j;
            const int s = r & 7;
#pragma unroll
            for (int n = 0; n < 4; ++n) {
                const int c = n * 16 + cl;
                ldsf[r * 64 + ((((c >> 2) ^ s) << 2) | (c & 3))] = acc[m][n][j];
            }
        }
    }
    asm volatile("" ::: "memory");   // DS pipe is in-order per wave; just pin program order

    const int q = cl;
    const int g = cg;
    const int col0 = bcol + wc * 64 + q * 4;
    const float4 sc = *(const float4*)(sq + col0);
    const float nac0 = -0.72134752f * sc.x;
    const float nac1 = -0.72134752f * sc.y;
    const float nac2 = -0.72134752f * sc.z;
    const float nac3 = -0.72134752f * sc.w;

#pragma unroll
    for (int k = 0; k < 16; ++k) {
        const int r = k * 4 + g;
        f32x4 v = *(const f32x4*)&ldsf[r * 64 + ((q ^ (r & 7)) << 2)];
        const int row = brow + wr * 64 + r;
        const float nar = -0.72134752f * sq[row];
        f32x4 o;
        o[0] = __builtin_exp2f(fminf(fmaf(v[0], 1.44269504f, nar + nac0), 0.f));
        o[1] = __builtin_exp2f(fminf(fmaf(v[1], 1.44269504f, nar + nac1), 0.f));
        o[2] = __builtin_exp2f(fminf(fmaf(v[2], 1.44269504f, nar + nac2), 0.f));
        o[3] = __builtin_exp2f(fminf(fmaf(v[3], 1.44269504f, nar + nac3), 0.f));
        *(f32x4*)(out + (size_t)row * MDIM + col0) = o;
    }
}

extern "C" void kernel_launch(void* const* d_in, const int* in_sizes, int n_in,
                              void* d_out, int out_size, void* d_ws, size_t ws_size,
                              hipStream_t stream) {
    const float* x = (const float*)d_in[0];
    float* out = (float*)d_out;

    float* sq = (float*)d_ws;
    unsigned short* xb = (unsigned short*)((char*)d_ws + MDIM * sizeof(float));

    rbf_convert<<<MDIM / 4, 256, 0, stream>>>(x, xb, sq);
    rbf_gemm<<<dim3(64 * 64), 256, 0, stream>>>(xb, sq, out);
}

// Round 4
// 101.801 us; speedup vs baseline: 1.2919x; 1.2919x over previous
//
#include <hip/hip_runtime.h>
#include <hip/hip_bf16.h>

#define MDIM 8192
#define KDIM 512
#define BM 128
#define BN 128
#define BK 64
#define NKT 8   // K-tiles of 64

typedef __attribute__((ext_vector_type(8))) short short8;
typedef __attribute__((ext_vector_type(4))) float f32x4;
typedef __attribute__((ext_vector_type(8))) unsigned short ushort8;

__device__ __forceinline__ unsigned short f32_to_bf16_rne(float f) {
    unsigned int u = __float_as_uint(f);
    u += 0x7FFFu + ((u >> 16) & 1u);
    return (unsigned short)(u >> 16);
}
__device__ __forceinline__ float bf16_to_f32(unsigned short s) {
    return __uint_as_float(((unsigned int)s) << 16);
}

__device__ __forceinline__ void gload16(const void* g, void* l) {
    __builtin_amdgcn_global_load_lds(
        (const __attribute__((address_space(1))) void*)g,
        (__attribute__((address_space(3))) void*)l,
        16, 0, 0);
}

// Kernel 1: fp32 -> bf16 into ws + sq[row] = sum(bf16(x)^2) (fp32).
__global__ __launch_bounds__(256) void rbf_convert(const float* __restrict__ x,
                                                   unsigned short* __restrict__ xb,
                                                   float* __restrict__ sq) {
    const int lane = threadIdx.x & 63;
    const int wave = threadIdx.x >> 6;
    const int row  = blockIdx.x * 4 + wave;

    const float* xr = x + (size_t)row * KDIM + lane * 8;
    float4 v0 = *(const float4*)(xr);
    float4 v1 = *(const float4*)(xr + 4);
    float vals[8] = {v0.x, v0.y, v0.z, v0.w, v1.x, v1.y, v1.z, v1.w};

    ushort8 packed;
    float s = 0.f;
#pragma unroll
    for (int j = 0; j < 8; ++j) {
        unsigned short b = f32_to_bf16_rne(vals[j]);
        packed[j] = b;
        float f = bf16_to_f32(b);
        s += f * f;
    }
    *(ushort8*)(xb + (size_t)row * KDIM + lane * 8) = packed;

#pragma unroll
    for (int off = 32; off > 0; off >>= 1) s += __shfl_xor(s, off, 64);
    if (lane == 0) sq[row] = s;
}

// Kernel 2: 128x128 NT-GEMM tile + RBF epilogue, XCD-banded schedule.
// XCD x (bid&7) owns A-rows [x*1024, x*1024+1024) -> L2-resident all kernel.
// B is swept in 8 bands of 1024 rows (1 MB); the 64 blocks of one band fill
// the XCD's concurrent capacity (32 CU x 2 blocks) so each band crosses the
// fabric once. Output stores are non-temporal so they don't evict the bands.
__global__ __launch_bounds__(256, 2) void rbf_gemm(const unsigned short* __restrict__ xb,
                                                   const float* __restrict__ sq,
                                                   float* __restrict__ out) {
    __shared__ char lds[65536];   // dbuf: [buf][A 16K | B 16K]; reused by epilogue

    const int t    = threadIdx.x;
    const int lane = t & 63;
    const int wave = t >> 6;
    const int wr   = wave >> 1;   // 0..1
    const int wc   = wave & 1;    // 0..1

    // XCD-banded mapping: bid&7 = XCD, then sequence = band(8) x arow(8) x bcol(8)
    const int bid  = blockIdx.x;
    const int xcd  = bid & 7;
    const int s    = bid >> 3;
    const int band = s >> 6;          // B col-band, sequential per XCD
    const int ar   = (s >> 3) & 7;    // A tile-row within the XCD's band
    const int bc   = s & 7;           // B tile-col within the band
    const int brow = xcd * 1024 + ar * 128;
    const int bcol = band * 1024 + bc * 128;

    // staging: thread t -> LDS row t>>3 (+32 per issue), physical slot t&7 (linear),
    // global source slot XOR-swizzled (T2 both-sides, involution verified R2).
    const int trow = t >> 3;                          // 0..31
    const int sx   = ((t & 7) ^ (trow & 7)) * 16;     // swizzled source byte slot

    // fragment coords
    const int fr = lane & 15;
    const int fo = lane >> 4;
    const int k7 = fr & 7;

    f32x4 acc[4][4] = {};

    const char* gA = (const char*)xb + (size_t)(brow + trow) * 1024 + sx;
    const char* gB = (const char*)xb + (size_t)(bcol + trow) * 1024 + sx;
    char* ldsw = lds + wave * 1024;   // wave-uniform base; +buf*32768 +op*16384 +u*4096

    // prologue: stage tile 0 into buf 0
#pragma unroll
    for (int u = 0; u < 4; ++u) {
        gload16(gA + (size_t)u * 32768, ldsw + u * 4096);
        gload16(gB + (size_t)u * 32768, ldsw + 16384 + u * 4096);
    }
    __syncthreads();

#pragma unroll
    for (int i = 0; i < NKT; ++i) {
        const int cb = i & 1;
        if (i < NKT - 1) {
            const size_t koff = (size_t)(i + 1) * 128;
            char* dst = ldsw + (cb ^ 1) * 32768;
#pragma unroll
            for (int u = 0; u < 4; ++u) {
                gload16(gA + (size_t)u * 32768 + koff, dst + u * 4096);
                gload16(gB + (size_t)u * 32768 + koff, dst + 16384 + u * 4096);
            }
        }
        const char* Ab = lds + cb * 32768;
        const char* Bb = lds + cb * 32768 + 16384;
#pragma unroll
        for (int ks = 0; ks < 2; ++ks) {
            const int cxa = ((ks * 4 + fo) ^ k7) * 16;
            short8 a[4];
#pragma unroll
            for (int m = 0; m < 4; ++m)
                a[m] = *(const short8*)(Ab + (wr * 64 + m * 16 + fr) * 128 + cxa);
#pragma unroll
            for (int n = 0; n < 4; ++n) {
                short8 b = *(const short8*)(Bb + (wc * 64 + n * 16 + fr) * 128 + cxa);
#pragma unroll
                for (int m = 0; m < 4; ++m)
                    acc[m][n] = __builtin_amdgcn_mfma_f32_16x16x32_bf16(a[m], b, acc[m][n], 0, 0, 0);
            }
        }
        __syncthreads();   // reads drained + next tile landed
    }

    // ---- epilogue: per-wave 16 KiB LDS transpose, nontemporal float4 stores ----
    float* ldsf = (float*)lds + wave * 4096;   // 64 rows x 64 f32, 16B-group XOR swizzle
    const int cg = lane >> 4;
    const int cl = lane & 15;

    asm volatile("" ::: "memory");
#pragma unroll
    for (int m = 0; m < 4; ++m) {
#pragma unroll
        for (int j = 0; j < 4; ++j) {
            const int r = m * 16 + cg * 4 + j;
            const int sxr = r & 7;
#pragma unroll
            for (int n = 0; n < 4; ++n) {
                const int c = n * 16 + cl;
                ldsf[r * 64 + ((((c >> 2) ^ sxr) << 2) | (c & 3))] = acc[m][n][j];
            }
        }
    }
    asm volatile("" ::: "memory");   // per-wave region; pin program order only

    const int q = cl;
    const int g = cg;
    const int col0 = bcol + wc * 64 + q * 4;
    const float4 sc = *(const float4*)(sq + col0);
    const float nac0 = -0.72134752f * sc.x;
    const float nac1 = -0.72134752f * sc.y;
    const float nac2 = -0.72134752f * sc.z;
    const float nac3 = -0.72134752f * sc.w;

#pragma unroll
    for (int k = 0; k < 16; ++k) {
        const int r = k * 4 + g;
        f32x4 v = *(const f32x4*)&ldsf[r * 64 + ((q ^ (r & 7)) << 2)];
        const int row = brow + wr * 64 + r;
        const float nar = -0.72134752f * sq[row];
        f32x4 o;
        o[0] = __builtin_exp2f(fminf(fmaf(v[0], 1.44269504f, nar + nac0), 0.f));
        o[1] = __builtin_exp2f(fminf(fmaf(v[1], 1.44269504f, nar + nac1), 0.f));
        o[2] = __builtin_exp2f(fminf(fmaf(v[2], 1.44269504f, nar + nac2), 0.f));
        o[3] = __builtin_exp2f(fminf(fmaf(v[3], 1.44269504f, nar + nac3), 0.f));
        __builtin_nontemporal_store(o, (f32x4*)(out + (size_t)row * MDIM + col0));
    }
}

extern "C" void kernel_launch(void* const* d_in, const int* in_sizes, int n_in,
                              void* d_out, int out_size, void* d_ws, size_t ws_size,
                              hipStream_t stream) {
    const float* x = (const float*)d_in[0];
    float* out = (float*)d_out;

    float* sq = (float*)d_ws;
    unsigned short* xb = (unsigned short*)((char*)d_ws + MDIM * sizeof(float));

    rbf_convert<<<MDIM / 4, 256, 0, stream>>>(x, xb, sq);
    rbf_gemm<<<dim3(64 * 64), 256, 0, stream>>>(xb, sq, out);
}

// Round 5
// 94.729 us; speedup vs baseline: 1.3884x; 1.0747x over previous
//
#include <hip/hip_runtime.h>
#include <hip/hip_bf16.h>

#define MDIM 8192
#define KDIM 512
#define BM 128
#define BN 128
#define BK 64
#define NKT 8   // K-tiles of 64

typedef __attribute__((ext_vector_type(8))) short short8;
typedef __attribute__((ext_vector_type(4))) float f32x4;
typedef __attribute__((ext_vector_type(8))) unsigned short ushort8;

__device__ __forceinline__ unsigned short f32_to_bf16_rne(float f) {
    unsigned int u = __float_as_uint(f);
    u += 0x7FFFu + ((u >> 16) & 1u);
    return (unsigned short)(u >> 16);
}
__device__ __forceinline__ float bf16_to_f32(unsigned short s) {
    return __uint_as_float(((unsigned int)s) << 16);
}

__device__ __forceinline__ void gload16(const void* g, void* l) {
    __builtin_amdgcn_global_load_lds(
        (const __attribute__((address_space(1))) void*)g,
        (__attribute__((address_space(3))) void*)l,
        16, 0, 0);
}

// Kernel 1: fp32 -> bf16 into ws + sq[row] = sum(bf16(x)^2) (fp32).
__global__ __launch_bounds__(256) void rbf_convert(const float* __restrict__ x,
                                                   unsigned short* __restrict__ xb,
                                                   float* __restrict__ sq) {
    const int lane = threadIdx.x & 63;
    const int wave = threadIdx.x >> 6;
    const int row  = blockIdx.x * 4 + wave;

    const float* xr = x + (size_t)row * KDIM + lane * 8;
    float4 v0 = *(const float4*)(xr);
    float4 v1 = *(const float4*)(xr + 4);
    float vals[8] = {v0.x, v0.y, v0.z, v0.w, v1.x, v1.y, v1.z, v1.w};

    ushort8 packed;
    float s = 0.f;
#pragma unroll
    for (int j = 0; j < 8; ++j) {
        unsigned short b = f32_to_bf16_rne(vals[j]);
        packed[j] = b;
        float f = bf16_to_f32(b);
        s += f * f;
    }
    *(ushort8*)(xb + (size_t)row * KDIM + lane * 8) = packed;

#pragma unroll
    for (int off = 32; off > 0; off >>= 1) s += __shfl_xor(s, off, 64);
    if (lane == 0) sq[row] = s;
}

// Kernel 2: symmetric RBF — lower-triangle 128x128 tiles only (2080 blocks),
// each block stores its tile AND the transposed tile (direct from registers,
// since MFMA C-layout is row-contiguous per lane along j).
// XCD x owns tile-rows {4x..4x+3, 60-4x..63-4x} (row-pairing => exactly 260
// tiles/XCD); B swept band-major for L2 residency. nt stores throughout.
__global__ __launch_bounds__(256, 2) void rbf_gemm(const unsigned short* __restrict__ xb,
                                                   const float* __restrict__ sq,
                                                   float* __restrict__ out) {
    __shared__ char lds[65536];   // dbuf: [buf][A 16K | B 16K]; reused by epilogue

    const int t    = threadIdx.x;
    const int lane = t & 63;
    const int wave = t >> 6;
    const int wr   = wave >> 1;   // 0..1
    const int wc   = wave & 1;    // 0..1

    // ---- triangular XCD-affine tile mapping ----
    const int bid = blockIdx.x;
    const int xcd = bid & 7;
    int kk = bid >> 3;            // 0..259
    int tr = 0, tc = 0;
    {
        bool found = false;
#pragma unroll 1
        for (int b = 0; b < 8 && !found; ++b) {
#pragma unroll 1
            for (int i = 0; i < 8; ++i) {
                const int rr = (i < 4) ? (4 * xcd + i) : (60 - 4 * xcd + (i - 4));
                int n = rr - 8 * b + 1;
                n = n < 0 ? 0 : (n > 8 ? 8 : n);
                if (kk < n) { tr = rr; tc = 8 * b + kk; found = true; break; }
                kk -= n;
            }
        }
    }
    const int brow = tr * 128;
    const int bcol = tc * 128;

    // staging: thread t -> LDS row t>>3 (+32 per issue), slot t&7 linear dest,
    // global source slot XOR-swizzled (T2 both-sides involution, verified R2-R4).
    const int trow = t >> 3;
    const int sx   = ((t & 7) ^ (trow & 7)) * 16;

    // fragment coords
    const int fr = lane & 15;
    const int fo = lane >> 4;
    const int k7 = fr & 7;

    f32x4 acc[4][4] = {};

    const char* gA = (const char*)xb + (size_t)(brow + trow) * 1024 + sx;
    const char* gB = (const char*)xb + (size_t)(bcol + trow) * 1024 + sx;
    char* ldsw = lds + wave * 1024;

    // prologue: stage tile 0 into buf 0
#pragma unroll
    for (int u = 0; u < 4; ++u) {
        gload16(gA + (size_t)u * 32768, ldsw + u * 4096);
        gload16(gB + (size_t)u * 32768, ldsw + 16384 + u * 4096);
    }
    __syncthreads();

#pragma unroll
    for (int i = 0; i < NKT; ++i) {
        const int cb = i & 1;
        if (i < NKT - 1) {
            const size_t koff = (size_t)(i + 1) * 128;
            char* dst = ldsw + (cb ^ 1) * 32768;
#pragma unroll
            for (int u = 0; u < 4; ++u) {
                gload16(gA + (size_t)u * 32768 + koff, dst + u * 4096);
                gload16(gB + (size_t)u * 32768 + koff, dst + 16384 + u * 4096);
            }
        }
        const char* Ab = lds + cb * 32768;
        const char* Bb = lds + cb * 32768 + 16384;
#pragma unroll
        for (int ks = 0; ks < 2; ++ks) {
            const int cxa = ((ks * 4 + fo) ^ k7) * 16;
            short8 a[4];
#pragma unroll
            for (int m = 0; m < 4; ++m)
                a[m] = *(const short8*)(Ab + (wr * 64 + m * 16 + fr) * 128 + cxa);
#pragma unroll
            for (int n = 0; n < 4; ++n) {
                short8 b = *(const short8*)(Bb + (wc * 64 + n * 16 + fr) * 128 + cxa);
#pragma unroll
                for (int m = 0; m < 4; ++m)
                    acc[m][n] = __builtin_amdgcn_mfma_f32_16x16x32_bf16(a[m], b, acc[m][n], 0, 0, 0);
            }
        }
        __syncthreads();
    }

    // ---- epilogue ----
    const int cg = lane >> 4;
    const int cl = lane & 15;

    // per-lane row/col norms (L2-hot scalar loads)
    float sqr[16], sqc[4];
#pragma unroll
    for (int m = 0; m < 4; ++m)
#pragma unroll
        for (int j = 0; j < 4; ++j)
            sqr[m * 4 + j] = sq[brow + wr * 64 + m * 16 + cg * 4 + j];
#pragma unroll
    for (int n = 0; n < 4; ++n)
        sqc[n] = sq[bcol + wc * 64 + n * 16 + cl];

    // exp once, in MFMA C-layout (in place)
#pragma unroll
    for (int m = 0; m < 4; ++m)
#pragma unroll
        for (int n = 0; n < 4; ++n)
#pragma unroll
            for (int j = 0; j < 4; ++j) {
                const float v = fmaf(acc[m][n][j], 1.44269504f,
                                     -0.72134752f * (sqr[m * 4 + j] + sqc[n]));
                acc[m][n][j] = __builtin_exp2f(fminf(v, 0.f));
            }

    // transposed tile store, direct from registers: tile[r][c] -> out[bcol+c][brow+r];
    // lane's j-axis (rows) is contiguous => f32x4 per (m,n).
    if (tr != tc) {
#pragma unroll
        for (int n = 0; n < 4; ++n) {
            float* orow = out + (size_t)(bcol + wc * 64 + n * 16 + cl) * MDIM
                              + brow + wr * 64 + cg * 4;
#pragma unroll
            for (int m = 0; m < 4; ++m)
                __builtin_nontemporal_store(acc[m][n], (f32x4*)(orow + m * 16));
        }
    }

    // normal tile store via per-wave LDS transpose (16B-group XOR swizzle, verified)
    float* ldsf = (float*)lds + wave * 4096;
    asm volatile("" ::: "memory");
#pragma unroll
    for (int m = 0; m < 4; ++m) {
#pragma unroll
        for (int j = 0; j < 4; ++j) {
            const int r = m * 16 + cg * 4 + j;
            const int sxr = r & 7;
#pragma unroll
            for (int n = 0; n < 4; ++n) {
                const int c = n * 16 + cl;
                ldsf[r * 64 + ((((c >> 2) ^ sxr) << 2) | (c & 3))] = acc[m][n][j];
            }
        }
    }
    asm volatile("" ::: "memory");   // per-wave LDS region; pin program order only

    const int col0 = bcol + wc * 64 + cl * 4;
#pragma unroll
    for (int k = 0; k < 16; ++k) {
        const int r = k * 4 + cg;
        f32x4 v = *(const f32x4*)&ldsf[r * 64 + ((cl ^ (r & 7)) << 2)];
        const int row = brow + wr * 64 + r;
        __builtin_nontemporal_store(v, (f32x4*)(out + (size_t)row * MDIM + col0));
    }
}

extern "C" void kernel_launch(void* const* d_in, const int* in_sizes, int n_in,
                              void* d_out, int out_size, void* d_ws, size_t ws_size,
                              hipStream_t stream) {
    const float* x = (const float*)d_in[0];
    float* out = (float*)d_out;

    float* sq = (float*)d_ws;
    unsigned short* xb = (unsigned short*)((char*)d_ws + MDIM * sizeof(float));

    rbf_convert<<<MDIM / 4, 256, 0, stream>>>(x, xb, sq);
    rbf_gemm<<<dim3(2080), 256, 0, stream>>>(xb, sq, out);
}